// Round 3
// baseline (10037.117 us; speedup 1.0000x reference)
//
#include <hip/hip_runtime.h>
#include <hip/hip_bf16.h>

// dims fixed by the problem
#define S_LEN 512
#define B_SZ  32
#define H_DIM 512
#define KC    1024   // 2H
#define NSG   4      // supergroups
#define SGB   64     // blocks per supergroup
#define NBT   8      // batches per supergroup

typedef __attribute__((ext_vector_type(8)))  short  short8;   // bf16x8
typedef __attribute__((ext_vector_type(4)))  float  f32x4;

static __device__ __forceinline__ unsigned short f2bf(float f){
  unsigned u = __float_as_uint(f);
  u += 0x7fffu + ((u >> 16) & 1u);          // RNE
  return (unsigned short)(u >> 16);
}
static __device__ __forceinline__ short8 cvt8(float4 a, float4 b){
  short8 r;
  r[0]=(short)f2bf(a.x); r[1]=(short)f2bf(a.y); r[2]=(short)f2bf(a.z); r[3]=(short)f2bf(a.w);
  r[4]=(short)f2bf(b.x); r[5]=(short)f2bf(b.y); r[6]=(short)f2bf(b.z); r[7]=(short)f2bf(b.w);
  return r;
}
static __device__ __forceinline__ float sigf(float x){ return 1.0f/(1.0f+__expf(-x)); }
static __device__ __forceinline__ float tanh_(float x){
  float e = __expf(2.0f*x);
  return (e-1.0f)/(e+1.0f);
}

// ---- IF-coherent (cache-bypass) accessors: relaxed agent atomics, NO fences ----
static __device__ __forceinline__ void stf_cc(float* p, float v){
  __hip_atomic_store(p, v, __ATOMIC_RELAXED, __HIP_MEMORY_SCOPE_AGENT);
}
static __device__ __forceinline__ float ldf_cc(const float* p){
  return __hip_atomic_load((float*)p, __ATOMIC_RELAXED, __HIP_MEMORY_SCOPE_AGENT);
}
static __device__ __forceinline__ float2 ld2_cc(const float* p){
  unsigned long long u = __hip_atomic_load((unsigned long long*)p, __ATOMIC_RELAXED, __HIP_MEMORY_SCOPE_AGENT);
  float2 r; r.x = __uint_as_float((unsigned)u); r.y = __uint_as_float((unsigned)(u>>32));
  return r;
}

// ------------------- gather / conversion kernels -------------------
__global__ __launch_bounds__(256) void k_gather_emb(const int* __restrict__ src,
    const float* __restrict__ Wemb, unsigned short* __restrict__ embB){
  int gid = blockIdx.x*256 + threadIdx.x;
  int row = gid >> 6;
  int k   = (gid & 63) * 8;
  int idx = src[row];
  const float* p = Wemb + (size_t)idx*H_DIM + k;
  float4 a = *(const float4*)p;
  float4 b = *(const float4*)(p+4);
  *(short8*)(embB + (size_t)gid*8) = cvt8(a,b);
}

__global__ __launch_bounds__(256) void k_perm_wr(const float* __restrict__ W,
    unsigned short* __restrict__ out){
  int gid = blockIdx.x*256 + threadIdx.x;
  int n = gid >> 6;
  int k = (gid & 63)*8;
  int j = (n&3)*512 + (n>>2);
  const float* p = W + (size_t)j*512 + k;
  float4 a = *(const float4*)p;
  float4 b = *(const float4*)(p+4);
  *(short8*)(out + (size_t)gid*8) = cvt8(a,b);
}

__global__ __launch_bounds__(256) void k_perm_wihw(const float* __restrict__ W,
    unsigned short* __restrict__ out){
  int gid = blockIdx.x*256 + threadIdx.x;
  int n = gid >> 7;
  int k = (gid & 127)*8;
  int j = (n&3)*512 + (n>>2);
  const float* p = W + (size_t)j*KC + k;
  float4 a = *(const float4*)p;
  float4 b = *(const float4*)(p+4);
  *(short8*)(out + (size_t)gid*8) = cvt8(a,b);
}

__global__ __launch_bounds__(256) void k_wcT(const float* __restrict__ Wc,
    unsigned short* __restrict__ out){
  __shared__ float tile[64][65];
  int bx = blockIdx.x & 15, by = blockIdx.x >> 4;
  int c0 = bx*64, r0 = by*64;
  int row = threadIdx.x >> 2;
  int cp  = (threadIdx.x & 3)*16;
  for (int i=0;i<16;i+=4){
    float4 v = *(const float4*)&Wc[(size_t)(r0+row)*KC + c0 + cp + i];
    tile[row][cp+i+0]=v.x; tile[row][cp+i+1]=v.y; tile[row][cp+i+2]=v.z; tile[row][cp+i+3]=v.w;
  }
  __syncthreads();
  short8 s0, s1;
  for(int i=0;i<8;++i){
    s0[i]=(short)f2bf(tile[cp+i][row]);
    s1[i]=(short)f2bf(tile[cp+8+i][row]);
  }
  unsigned short* op = out + (size_t)(c0+row)*KC + r0 + cp;
  *(short8*)op = s0; *(short8*)(op+8) = s1;
}

__global__ __launch_bounds__(256) void k_bias_r(const float* __restrict__ bi,
    const float* __restrict__ bh, float* __restrict__ out){
  int n = blockIdx.x*256 + threadIdx.x;
  int j = (n&3)*512 + (n>>2);
  out[n] = bi[j] + bh[j];
}

__global__ __launch_bounds__(256) void k_bcomb(const float* __restrict__ Wihw,
    const float* __restrict__ bc, const float* __restrict__ bi,
    const float* __restrict__ bh, float* __restrict__ out){
  int n = blockIdx.x*256 + threadIdx.x;
  int j = (n&3)*512 + (n>>2);
  const float* wp = Wihw + (size_t)j*KC;
  float s = 0.f;
  for (int l=0;l<KC;l+=4){
    float4 w = *(const float4*)&wp[l];
    float4 c = *(const float4*)&bc[l];
    s += w.x*c.x + w.y*c.y + w.z*c.z + w.w*c.w;
  }
  out[n] = s + bi[j] + bh[j];
}

// ------------------- bf16 MFMA GEMM  C = A·Bm^T -------------------
template<int EPI>
__global__ __launch_bounds__(256) void gemm_k(const unsigned short* __restrict__ A,
    const unsigned short* __restrict__ Bm, int K, int bnCnt,
    const float* __restrict__ bias, float* __restrict__ outF,
    unsigned short* __restrict__ outB, int outStride){
  __shared__ __align__(16) char smem[66560];
  unsigned short* As = (unsigned short*)smem;
  unsigned short* Bs = As + 128*72;
  float* epi = (float*)smem;
  const int tid = threadIdx.x, lane = tid & 63, w = tid >> 6;
  const int wr = w >> 1, wc = w & 1;
  const int bm = blockIdx.x / bnCnt, bn = blockIdx.x % bnCnt;
  f32x4 acc[4][4] = {};
  const size_t Abase = (size_t)bm*128*K;
  const size_t Bbase = (size_t)bn*128*K;
  for (int k0 = 0; k0 < K; k0 += 64){
    __syncthreads();
    #pragma unroll
    for (int i = 0; i < 4; ++i){
      int idx = tid + i*256;
      int row = idx >> 3, cb = (idx & 7)*8;
      *(short8*)&As[row*72 + cb] = *(const short8*)&A[Abase + (size_t)row*K + k0 + cb];
      *(short8*)&Bs[row*72 + cb] = *(const short8*)&Bm[Bbase + (size_t)row*K + k0 + cb];
    }
    __syncthreads();
    #pragma unroll
    for (int kk = 0; kk < 64; kk += 32){
      short8 af[4], bf[4];
      #pragma unroll
      for (int i=0;i<4;++i) af[i] = *(short8*)&As[(wr*64 + i*16 + (lane&15))*72 + kk + (lane>>4)*8];
      #pragma unroll
      for (int j=0;j<4;++j) bf[j] = *(short8*)&Bs[(wc*64 + j*16 + (lane&15))*72 + kk + (lane>>4)*8];
      #pragma unroll
      for (int i=0;i<4;++i)
        #pragma unroll
        for (int j=0;j<4;++j)
          acc[i][j] = __builtin_amdgcn_mfma_f32_16x16x32_bf16(af[i], bf[j], acc[i][j], 0,0,0);
    }
  }
  if (EPI == 0){
    float bj[4];
    #pragma unroll
    for (int j=0;j<4;++j) bj[j] = bias[bn*128 + wc*64 + j*16 + (lane&15)];
    __syncthreads();
    float* ep = epi + w*(64*65);
    #pragma unroll
    for (int i=0;i<4;++i)
      #pragma unroll
      for (int j=0;j<4;++j)
        #pragma unroll
        for (int r=0;r<4;++r)
          ep[(i*16 + (lane>>4)*4 + r)*65 + j*16 + (lane&15)] = acc[i][j][r] + bj[j];
    __syncthreads();
    int rg = bm*128 + wr*64 + lane;
    #pragma unroll
    for (int q=0;q<16;++q){
      float gi = ep[lane*65 + q*4+0];
      float gg = ep[lane*65 + q*4+2];
      float go = ep[lane*65 + q*4+3];
      float c = sigf(gi)*tanh_(gg);
      float h = sigf(go)*tanh_(c);
      outF[(size_t)rg*H_DIM + bn*32 + wc*16 + q] = h;
    }
  } else {
    #pragma unroll
    for (int i=0;i<4;++i)
      #pragma unroll
      for (int j=0;j<4;++j)
        #pragma unroll
        for (int r=0;r<4;++r){
          int rg = bm*128 + wr*64 + i*16 + (lane>>4)*4 + r;
          int cg = bn*128 + wc*64 + j*16 + (lane&15);
          outB[(size_t)rg*outStride + cg] = f2bf(acc[i][j][r]);
        }
  }
}

// ------------------- persistent scan kernel -------------------
// Supergroup barrier: flag-array (no hub). Each block stores its flag (IF),
// wave 0 of every block polls all 64 flags. __syncthreads drains vmcnt per
// wave before the flag store (compiler-emitted), so prior stores/atomics are
// IF-visible when the flag lands.
static __device__ __forceinline__ void sgBar(int* flg, int c, int tid, int lane, int k){
  __syncthreads();
  asm volatile("s_waitcnt vmcnt(0)" ::: "memory");
  if (tid == 0)
    __hip_atomic_store(&flg[c], k, __ATOMIC_RELAXED, __HIP_MEMORY_SCOPE_AGENT);
  if (tid < 64){
    for (;;){
      int v = __hip_atomic_load(&flg[lane], __ATOMIC_RELAXED, __HIP_MEMORY_SCOPE_AGENT);
      if (__all(v >= k)) break;
      __builtin_amdgcn_s_sleep(1);
    }
  }
  __syncthreads();
  asm volatile("" ::: "memory");
}

static __device__ __forceinline__ float blockReduce(float v, bool isMax, float* red4, int lane, int wv){
  #pragma unroll
  for (int m=32;m>0;m>>=1){
    float o = __shfl_xor(v, m);
    v = isMax ? fmaxf(v,o) : v+o;
  }
  __syncthreads();
  if (lane==0) red4[wv] = v;
  __syncthreads();
  float r0=red4[0], r1=red4[1], r2=red4[2], r3=red4[3];
  return isMax ? fmaxf(fmaxf(r0,r1),fmaxf(r2,r3)) : (r0+r1)+(r2+r3);
}

// Supergroup sg = bid>>6 owns batches 8sg..8sg+7 (64 blocks).
// A-role: block c=bid&63 -> batch b=8sg+(c&7), chunk=c>>3 (M rows chunk*64..+64 in LDS).
// B-role: block computes gate cols [c*32, c*32+32) for its supergroup's 8 batches
// via 16x16x32 MFMA (8 valid rows), K split over 4 waves.
__global__ __launch_bounds__(256,1) void scan_k(
    const int* __restrict__ src, const float* __restrict__ Wemb,
    const float* __restrict__ o_all, const unsigned short* __restrict__ Wcomb,
    const float* __restrict__ bcomb,
    float* __restrict__ dbuf, float* __restrict__ zbuf, float* __restrict__ mglob,
    float* __restrict__ hbuf, float* __restrict__ hdotb, float* __restrict__ out,
    int* __restrict__ flags){
  __shared__ __align__(16) float Mrow[64*512];   // 128 KB
  __shared__ __align__(16) float scratch[2048];  // m-stage [4][512] / gw [4][8][32]
  __shared__ float red4[4];
  __shared__ float zt_own[64];
  __shared__ float zp_own[64];

  const int tid = threadIdx.x, lane = tid & 63, wv = tid >> 6;
  const int bid = blockIdx.x;
  const int sg = bid >> 6, c = bid & 63;
  const int b = sg*NBT + (c & 7), chunk = c >> 3;
  const int cbase = chunk*64;
  const int n0 = c*32;                       // B-role gate-col base
  int* flg = flags + sg*SGB;
  const int cA = lane*4, cB = 256 + lane*4;  // conflict-free float4 columns

  // ---- init: zero parity buffers, gather M0 rows, prime d_0 ----
  if (tid < 64){
    stf_cc(&zbuf[((size_t)1*B_SZ + b)*S_LEN + cbase + tid], 0.f);   // z_{-1}=0
    stf_cc(&hbuf[((size_t)1*B_SZ + b)*H_DIM + cbase + tid], 0.f);   // h_{-1}
    stf_cc(&mglob[((size_t)0*B_SZ + b)*H_DIM + cbase + tid], 0.f);  // m parity 0
  }
  if (c == 0 && tid < 16)
    stf_cc(&hdotb[(tid>>3)*B_SZ + sg*NBT + (tid&7)], 0.f);
  {
    const float* o0 = o_all + (size_t)b*H_DIM;
    float4 osA = *(const float4*)&o0[cA];
    float4 osB = *(const float4*)&o0[cB];
    for (int rr=0; rr<16; ++rr){
      int lr = wv*16 + rr;
      int sgl = cbase + lr;
      int idx = src[sgl*B_SZ + b];
      const float* wp = Wemb + (size_t)idx*H_DIM;
      float4 v0 = *(const float4*)&wp[cA];
      float4 v1 = *(const float4*)&wp[cB];
      *(float4*)&Mrow[lr*512 + cA] = v0;
      *(float4*)&Mrow[lr*512 + cB] = v1;
      float dd = v0.x*osA.x + v0.y*osA.y + v0.z*osA.z + v0.w*osA.w
               + v1.x*osB.x + v1.y*osB.y + v1.z*osB.z + v1.w*osB.w;
      #pragma unroll
      for (int m=32;m>0;m>>=1) dd += __shfl_xor(dd, m);
      if (lane==0) stf_cc(&dbuf[(size_t)b*S_LEN + sgl], dd);   // d_0, parity 0
    }
  }
  sgBar(flg, c, tid, lane, 1);

  for (int t=0; t<S_LEN; ++t){
    const int pw = t & 1, po = pw ^ 1;
    const float* dR = dbuf + ((size_t)pw*B_SZ + b)*S_LEN;   // d_t
    const float* zR = zbuf + ((size_t)po*B_SZ + b)*S_LEN;   // z_{t-1}
    float* zW = zbuf + ((size_t)pw*B_SZ + b)*S_LEN;         // z_t
    float* dW = dbuf + ((size_t)po*B_SZ + b)*S_LEN;         // d_{t+1}
    const float* hR = hbuf + ((size_t)po*B_SZ + b)*H_DIM;   // h_{t-1}

    // ---- top loads (all IF traffic issued up front) ----
    float hd  = ldf_cc(&hdotb[pw*B_SZ + b]);                // h_{t-1}·o_t
    float zp0 = ldf_cc(&zR[tid]),     zp1 = ldf_cc(&zR[tid+256]);
    float d0  = ldf_cc(&dR[tid]),     d1  = ldf_cc(&dR[tid+256]);
    float2 h0 = ld2_cc(&hR[cA]), h1 = ld2_cc(&hR[cA+2]);
    float2 h2 = ld2_cc(&hR[cB]), h3 = ld2_cc(&hR[cB+2]);
    float4 hsA = make_float4(h0.x,h0.y,h1.x,h1.y);
    float4 hsB = make_float4(h2.x,h2.y,h3.x,h3.y);

    // ---- scores + softmax ----
    float sc0 = (1.f - zp0)*d0 + zp0*hd;
    float sc1 = (1.f - zp1)*d1 + zp1*hd;
    float mx = blockReduce(fmaxf(sc0,sc1), true, red4, lane, wv);
    float ex0 = __expf(sc0 - mx), ex1 = __expf(sc1 - mx);
    float sm = blockReduce(ex0+ex1, false, red4, lane, wv);
    float inv = 1.f / sm;
    if ((unsigned)(tid - cbase) < 64u){
      zt_own[tid-cbase] = ex0*inv; zp_own[tid-cbase] = zp0; stf_cc(&zW[tid], ex0*inv);
    }
    if ((unsigned)(tid + 256 - cbase) < 64u){
      zt_own[tid+256-cbase] = ex1*inv; zp_own[tid+256-cbase] = zp1; stf_cc(&zW[tid+256], ex1*inv);
    }
    __syncthreads();

    // ---- single M sweep: pending update + m accum + next-d dot ----
    const bool hasNext = (t < S_LEN-1);
    const float* onx = o_all + ((size_t)(hasNext? t+1 : t)*B_SZ + b)*H_DIM;
    float4 osA = *(const float4*)&onx[cA];
    float4 osB = *(const float4*)&onx[cB];
    float m0=0,m1=0,m2=0,m3=0,m4=0,m5=0,m6=0,m7=0;
    for (int rr=0; rr<16; ++rr){
      int lr = wv*16 + rr;
      float zp = zp_own[lr], zt = zt_own[lr];
      float* mpA = &Mrow[lr*512 + cA];
      float* mpB = &Mrow[lr*512 + cB];
      float4 v0 = *(float4*)mpA;
      float4 v1 = *(float4*)mpB;
      v0.x += zp*(hsA.x - v0.x); v0.y += zp*(hsA.y - v0.y);
      v0.z += zp*(hsA.z - v0.z); v0.w += zp*(hsA.w - v0.w);
      v1.x += zp*(hsB.x - v1.x); v1.y += zp*(hsB.y - v1.y);
      v1.z += zp*(hsB.z - v1.z); v1.w += zp*(hsB.w - v1.w);
      *(float4*)mpA = v0; *(float4*)mpB = v1;
      m0 += zt*v0.x; m1 += zt*v0.y; m2 += zt*v0.z; m3 += zt*v0.w;
      m4 += zt*v1.x; m5 += zt*v1.y; m6 += zt*v1.z; m7 += zt*v1.w;
      float dd = v0.x*osA.x + v0.y*osA.y + v0.z*osA.z + v0.w*osA.w
               + v1.x*osB.x + v1.y*osB.y + v1.z*osB.z + v1.w*osB.w;
      #pragma unroll
      for (int m=32;m>0;m>>=1) dd += __shfl_xor(dd, m);
      if (lane==0 && hasNext) stf_cc(&dW[cbase + lr], dd);
    }
    __syncthreads();
    *(float4*)&scratch[wv*512 + cA] = make_float4(m0,m1,m2,m3);
    *(float4*)&scratch[wv*512 + cB] = make_float4(m4,m5,m6,m7);
    __syncthreads();
    {
      int i0 = tid*2;
      float a0 = scratch[i0]   + scratch[512+i0]   + scratch[1024+i0]   + scratch[1536+i0];
      float a1 = scratch[i0+1] + scratch[512+i0+1] + scratch[1024+i0+1] + scratch[1536+i0+1];
      float* mg = mglob + ((size_t)pw*B_SZ + b)*H_DIM;
      atomicAdd(&mg[i0],   a0);
      atomicAdd(&mg[i0+1], a1);
    }
    sgBar(flg, c, tid, lane, 2*t+2);

    // ---- phase B: gates[8 batches][32 cols] = [o_t|m_t]·W_comb^T ----
    {
      // parity housekeeping (safe: targets not read/written by anyone this phase)
      if (tid < 64) stf_cc(&mglob[((size_t)po*B_SZ + b)*H_DIM + cbase + tid], 0.f);
      if (c == 0 && tid < 8) stf_cc(&hdotb[pw*B_SZ + sg*NBT + tid], 0.f);

      const int r15 = lane & 15, kq = lane >> 4;
      const int bqr = sg*NBT + (r15 & 7);          // A-row batch (rows 8-15 dup)
      const float* xo = o_all + ((size_t)t*B_SZ + bqr)*H_DIM;
      const float* xm = mglob + ((size_t)pw*B_SZ + bqr)*H_DIM;
      const unsigned short* wp0 = Wcomb + (size_t)(n0 + r15)*KC;
      const unsigned short* wp1 = Wcomb + (size_t)(n0 + 16 + r15)*KC;
      f32x4 acc0 = {0,0,0,0}, acc1 = {0,0,0,0};
      #pragma unroll
      for (int kt=0; kt<8; ++kt){
        int k = wv*256 + kt*32 + kq*8;
        float4 xa, xc;
        if (wv < 2){
          xa = *(const float4*)&xo[k];
          xc = *(const float4*)&xo[k+4];
        } else {
          const float* xp = xm + (k - 512);
          float2 p0 = ld2_cc(xp),   p1 = ld2_cc(xp+2);
          float2 p2 = ld2_cc(xp+4), p3 = ld2_cc(xp+6);
          xa = make_float4(p0.x,p0.y,p1.x,p1.y);
          xc = make_float4(p2.x,p2.y,p3.x,p3.y);
        }
        short8 af = cvt8(xa, xc);
        short8 b0 = *(const short8*)&wp0[k];
        short8 b1 = *(const short8*)&wp1[k];
        acc0 = __builtin_amdgcn_mfma_f32_16x16x32_bf16(af, b0, acc0, 0,0,0);
        acc1 = __builtin_amdgcn_mfma_f32_16x16x32_bf16(af, b1, acc1, 0,0,0);
      }
      __syncthreads();                 // scratch free for gw
      if (lane < 32){
        int rb = (lane>>4)*4;          // C row base (batches)
        float* gw = scratch + wv*256;  // [8][32]
        #pragma unroll
        for (int r=0;r<4;++r){
          gw[(rb+r)*32 + r15]      = acc0[r];
          gw[(rb+r)*32 + 16 + r15] = acc1[r];
        }
      }
      __syncthreads();
      if (tid < 64){
        int q = tid >> 3, p = tid & 7;
        int bq = sg*NBT + q;
        float g4[4];
        #pragma unroll
        for (int g=0; g<4; ++g){
          int col = p*4 + g;
          g4[g] = scratch[q*32+col] + scratch[256+q*32+col]
                + scratch[512+q*32+col] + scratch[768+q*32+col]
                + bcomb[n0 + col];
        }
        float ccv = sigf(g4[0])*tanh_(g4[2]);
        float hh  = sigf(g4[3])*tanh_(ccv);
        int hpos = c*8 + p;
        stf_cc(&hbuf[((size_t)pw*B_SZ + bq)*H_DIM + hpos], hh);
        out[((size_t)t*B_SZ + bq)*H_DIM + hpos] = hh;
        if (t == S_LEN-1){
          out[(size_t)S_LEN*B_SZ*H_DIM + (size_t)bq*H_DIM + hpos] = hh;
          out[(size_t)S_LEN*B_SZ*H_DIM + (size_t)B_SZ*H_DIM + (size_t)bq*H_DIM + hpos] = ccv;
        }
        // hdot_{t+1} partial: h_t · o_{t+1}
        int tn = (t < S_LEN-1) ? t+1 : t;
        float v = hh * o_all[((size_t)tn*B_SZ + bq)*H_DIM + hpos];
        v += __shfl_xor(v,1); v += __shfl_xor(v,2); v += __shfl_xor(v,4);
        if (p == 0 && t < S_LEN-1) atomicAdd(&hdotb[po*B_SZ + bq], v);
      }
    }
    sgBar(flg, c, tid, lane, 2*t+3);
  }
}

// ------------------- host launch -------------------
extern "C" void kernel_launch(void* const* d_in, const int* in_sizes, int n_in,
                              void* d_out, int out_size, void* d_ws, size_t ws_size,
                              hipStream_t stream){
  const int*   src   = (const int*)  d_in[0];
  const float* Wemb  = (const float*)d_in[1];
  const float* Wihr  = (const float*)d_in[2];
  const float* bihr  = (const float*)d_in[3];
  const float* bhhr  = (const float*)d_in[4];
  const float* Wc    = (const float*)d_in[5];
  const float* bc    = (const float*)d_in[6];
  const float* Wihw  = (const float*)d_in[7];
  const float* bihw  = (const float*)d_in[8];
  const float* bhhw  = (const float*)d_in[9];
  float* out = (float*)d_out;

  char* ws = (char*)d_ws;
  size_t off = 0;
  auto alloc = [&](size_t bytes)->char*{
    char* p = ws + off; off += (bytes + 255) & ~(size_t)255; return p;
  };
  unsigned short* embB  = (unsigned short*)alloc((size_t)16384*512*2);
  float*          o_all = (float*)         alloc((size_t)16384*512*4);
  unsigned short* WrP   = (unsigned short*)alloc((size_t)2048*512*2);
  unsigned short* WiwP  = (unsigned short*)alloc((size_t)2048*1024*2);
  unsigned short* WcT   = (unsigned short*)alloc((size_t)1024*1024*2);
  unsigned short* Wcomb = (unsigned short*)alloc((size_t)2048*1024*2);
  float*          bperm = (float*)alloc(2048*4);
  float*          bcomb = (float*)alloc(2048*4);
  float*          dbuf  = (float*)alloc((size_t)2*32*512*4);
  float*          zbuf  = (float*)alloc((size_t)2*32*512*4);
  float*          mglob = (float*)alloc((size_t)2*32*512*4);
  float*          hbuf  = (float*)alloc((size_t)2*32*512*4);
  float*          hdotb = (float*)alloc((size_t)2*32*4);
  int*            flags = (int*)alloc(NSG*SGB*4);

  hipMemsetAsync(flags, 0, NSG*SGB*4, stream);
  k_gather_emb<<<4096,256,0,stream>>>(src, Wemb, embB);
  k_perm_wr  <<<512, 256,0,stream>>>(Wihr, WrP);
  k_perm_wihw<<<1024,256,0,stream>>>(Wihw, WiwP);
  k_wcT      <<<256, 256,0,stream>>>(Wc, WcT);
  k_bias_r   <<<8,   256,0,stream>>>(bihr, bhhr, bperm);
  k_bcomb    <<<8,   256,0,stream>>>(Wihw, bc, bihw, bhhw, bcomb);
  gemm_k<0><<<2048,256,0,stream>>>(embB, WrP, 512, 16, bperm, o_all, nullptr, 0);
  gemm_k<1><<<128,256,0,stream>>>(WiwP, WcT, 1024, 8, nullptr, nullptr, Wcomb, 1024);
  scan_k<<<256,256,0,stream>>>(src, Wemb, o_all, Wcomb, bcomb,
                               dbuf, zbuf, mglob, hbuf, hdotb, out, flags);
}

// Round 6
// 7618.491 us; speedup vs baseline: 1.3175x; 1.3175x over previous
//
#include <hip/hip_runtime.h>
#include <hip/hip_bf16.h>

// dims fixed by the problem
#define S_LEN 512
#define B_SZ  32
#define H_DIM 512
#define KC    1024   // 2H

typedef __attribute__((ext_vector_type(8)))  short  short8;   // bf16x8
typedef __attribute__((ext_vector_type(4)))  float  f32x4;
typedef __attribute__((ext_vector_type(2)))  float  f32x2;

static __device__ __forceinline__ unsigned short f2bf(float f){
  unsigned u = __float_as_uint(f);
  u += 0x7fffu + ((u >> 16) & 1u);          // RNE
  return (unsigned short)(u >> 16);
}
static __device__ __forceinline__ short8 cvt8(float4 a, float4 b){
  short8 r;
  r[0]=(short)f2bf(a.x); r[1]=(short)f2bf(a.y); r[2]=(short)f2bf(a.z); r[3]=(short)f2bf(a.w);
  r[4]=(short)f2bf(b.x); r[5]=(short)f2bf(b.y); r[6]=(short)f2bf(b.z); r[7]=(short)f2bf(b.w);
  return r;
}
static __device__ __forceinline__ short8 cvt8e(f32x4 a, f32x4 b){
  short8 r;
  r[0]=(short)f2bf(a[0]); r[1]=(short)f2bf(a[1]); r[2]=(short)f2bf(a[2]); r[3]=(short)f2bf(a[3]);
  r[4]=(short)f2bf(b[0]); r[5]=(short)f2bf(b[1]); r[6]=(short)f2bf(b[2]); r[7]=(short)f2bf(b[3]);
  return r;
}
static __device__ __forceinline__ float sigf(float x){ return 1.0f/(1.0f+__expf(-x)); }
static __device__ __forceinline__ float tanh_(float x){
  float e = __expf(2.0f*x);
  return (e-1.0f)/(e+1.0f);
}

// ---- MALL-coherent (AGENT scope) accessors — the round-2-proven semantics ----
static __device__ __forceinline__ void st_ag(float* p, float v){
  __hip_atomic_store(p, v, __ATOMIC_RELAXED, __HIP_MEMORY_SCOPE_AGENT);
}
static __device__ __forceinline__ f32x2 ld2_ag(const float* p){
  unsigned long long u = __hip_atomic_load((unsigned long long*)p, __ATOMIC_RELAXED, __HIP_MEMORY_SCOPE_AGENT);
  f32x2 r; r[0] = __uint_as_float((unsigned)u); r[1] = __uint_as_float((unsigned)(u>>32));
  return r;
}

// ------------------- gather / conversion kernels -------------------
__global__ __launch_bounds__(256) void k_gather_emb(const int* __restrict__ src,
    const float* __restrict__ Wemb, unsigned short* __restrict__ embB){
  int gid = blockIdx.x*256 + threadIdx.x;
  int row = gid >> 6;
  int k   = (gid & 63) * 8;
  int idx = src[row];
  const float* p = Wemb + (size_t)idx*H_DIM + k;
  float4 a = *(const float4*)p;
  float4 b = *(const float4*)(p+4);
  *(short8*)(embB + (size_t)gid*8) = cvt8(a,b);
}

__global__ __launch_bounds__(256) void k_perm_wr(const float* __restrict__ W,
    unsigned short* __restrict__ out){
  int gid = blockIdx.x*256 + threadIdx.x;
  int n = gid >> 6;
  int k = (gid & 63)*8;
  int j = (n&3)*512 + (n>>2);
  const float* p = W + (size_t)j*512 + k;
  float4 a = *(const float4*)p;
  float4 b = *(const float4*)(p+4);
  *(short8*)(out + (size_t)gid*8) = cvt8(a,b);
}

__global__ __launch_bounds__(256) void k_perm_wihw(const float* __restrict__ W,
    unsigned short* __restrict__ out){
  int gid = blockIdx.x*256 + threadIdx.x;
  int n = gid >> 7;
  int k = (gid & 127)*8;
  int j = (n&3)*512 + (n>>2);
  const float* p = W + (size_t)j*KC + k;
  float4 a = *(const float4*)p;
  float4 b = *(const float4*)(p+4);
  *(short8*)(out + (size_t)gid*8) = cvt8(a,b);
}

__global__ __launch_bounds__(256) void k_wcT(const float* __restrict__ Wc,
    unsigned short* __restrict__ out){
  __shared__ float tile[64][65];
  int bx = blockIdx.x & 15, by = blockIdx.x >> 4;
  int c0 = bx*64, r0 = by*64;
  int row = threadIdx.x >> 2;
  int cp  = (threadIdx.x & 3)*16;
  for (int i=0;i<16;i+=4){
    float4 v = *(const float4*)&Wc[(size_t)(r0+row)*KC + c0 + cp + i];
    tile[row][cp+i+0]=v.x; tile[row][cp+i+1]=v.y; tile[row][cp+i+2]=v.z; tile[row][cp+i+3]=v.w;
  }
  __syncthreads();
  short8 s0, s1;
  for(int i=0;i<8;++i){
    s0[i]=(short)f2bf(tile[cp+i][row]);
    s1[i]=(short)f2bf(tile[cp+8+i][row]);
  }
  unsigned short* op = out + (size_t)(c0+row)*KC + r0 + cp;
  *(short8*)op = s0; *(short8*)(op+8) = s1;
}

__global__ __launch_bounds__(256) void k_bias_r(const float* __restrict__ bi,
    const float* __restrict__ bh, float* __restrict__ out){
  int n = blockIdx.x*256 + threadIdx.x;
  int j = (n&3)*512 + (n>>2);
  out[n] = bi[j] + bh[j];
}

__global__ __launch_bounds__(256) void k_bcomb(const float* __restrict__ Wihw,
    const float* __restrict__ bc, const float* __restrict__ bi,
    const float* __restrict__ bh, float* __restrict__ out){
  int n = blockIdx.x*256 + threadIdx.x;
  int j = (n&3)*512 + (n>>2);
  const float* wp = Wihw + (size_t)j*KC;
  float s = 0.f;
  for (int l=0;l<KC;l+=4){
    float4 w = *(const float4*)&wp[l];
    float4 c = *(const float4*)&bc[l];
    s += w.x*c.x + w.y*c.y + w.z*c.z + w.w*c.w;
  }
  out[n] = s + bi[j] + bh[j];
}

// ------------------- bf16 MFMA GEMM  C = A·Bm^T -------------------
template<int EPI>
__global__ __launch_bounds__(256) void gemm_k(const unsigned short* __restrict__ A,
    const unsigned short* __restrict__ Bm, int K, int bnCnt,
    const float* __restrict__ bias, float* __restrict__ outF,
    unsigned short* __restrict__ outB, int outStride){
  __shared__ __align__(16) char smem[66560];
  unsigned short* As = (unsigned short*)smem;
  unsigned short* Bs = As + 128*72;
  float* epi = (float*)smem;
  const int tid = threadIdx.x, lane = tid & 63, w = tid >> 6;
  const int wr = w >> 1, wc = w & 1;
  const int bm = blockIdx.x / bnCnt, bn = blockIdx.x % bnCnt;
  f32x4 acc[4][4] = {};
  const size_t Abase = (size_t)bm*128*K;
  const size_t Bbase = (size_t)bn*128*K;
  for (int k0 = 0; k0 < K; k0 += 64){
    __syncthreads();
    #pragma unroll
    for (int i = 0; i < 4; ++i){
      int idx = tid + i*256;
      int row = idx >> 3, cb = (idx & 7)*8;
      *(short8*)&As[row*72 + cb] = *(const short8*)&A[Abase + (size_t)row*K + k0 + cb];
      *(short8*)&Bs[row*72 + cb] = *(const short8*)&Bm[Bbase + (size_t)row*K + k0 + cb];
    }
    __syncthreads();
    #pragma unroll
    for (int kk = 0; kk < 64; kk += 32){
      short8 af[4], bf[4];
      #pragma unroll
      for (int i=0;i<4;++i) af[i] = *(short8*)&As[(wr*64 + i*16 + (lane&15))*72 + kk + (lane>>4)*8];
      #pragma unroll
      for (int j=0;j<4;++j) bf[j] = *(short8*)&Bs[(wc*64 + j*16 + (lane&15))*72 + kk + (lane>>4)*8];
      #pragma unroll
      for (int i=0;i<4;++i)
        #pragma unroll
        for (int j=0;j<4;++j)
          acc[i][j] = __builtin_amdgcn_mfma_f32_16x16x32_bf16(af[i], bf[j], acc[i][j], 0,0,0);
    }
  }
  if (EPI == 0){
    float bj[4];
    #pragma unroll
    for (int j=0;j<4;++j) bj[j] = bias[bn*128 + wc*64 + j*16 + (lane&15)];
    __syncthreads();
    float* ep = epi + w*(64*65);
    #pragma unroll
    for (int i=0;i<4;++i)
      #pragma unroll
      for (int j=0;j<4;++j)
        #pragma unroll
        for (int r=0;r<4;++r)
          ep[(i*16 + (lane>>4)*4 + r)*65 + j*16 + (lane&15)] = acc[i][j][r] + bj[j];
    __syncthreads();
    int rg = bm*128 + wr*64 + lane;
    #pragma unroll
    for (int q=0;q<16;++q){
      float gi = ep[lane*65 + q*4+0];
      float gg = ep[lane*65 + q*4+2];
      float go = ep[lane*65 + q*4+3];
      float c = sigf(gi)*tanh_(gg);
      float h = sigf(go)*tanh_(c);
      outF[(size_t)rg*H_DIM + bn*32 + wc*16 + q] = h;
    }
  } else {
    #pragma unroll
    for (int i=0;i<4;++i)
      #pragma unroll
      for (int j=0;j<4;++j)
        #pragma unroll
        for (int r=0;r<4;++r){
          int rg = bm*128 + wr*64 + i*16 + (lane>>4)*4 + r;
          int cg = bn*128 + wc*64 + j*16 + (lane&15);
          outB[(size_t)rg*outStride + cg] = f2bf(acc[i][j][r]);
        }
  }
}

// ------------------- persistent scan kernel -------------------
// Groups fixed by bid: g = bid&7 -> 32 blocks, 4 batches; groups fully
// independent (no grid-wide sync anywhere). Barrier = one shared AGENT
// counter per group: each block's tid0 does one fetch_add then polls one
// MALL address. All cross-block data uses AGENT relaxed atomics (round-2
// proven). No workgroup-scope atomics, no sc0 asm, no XCC_ID probing.
static __device__ __forceinline__ void gbar(int* cnt, int tid, int target){
  __syncthreads();
  asm volatile("s_waitcnt vmcnt(0)" ::: "memory");
  if (tid == 0){
    __hip_atomic_fetch_add(cnt, 1, __ATOMIC_RELAXED, __HIP_MEMORY_SCOPE_AGENT);
    while (__hip_atomic_load(cnt, __ATOMIC_RELAXED, __HIP_MEMORY_SCOPE_AGENT) < target)
      __builtin_amdgcn_s_sleep(1);
  }
  __syncthreads();
  asm volatile("" ::: "memory");
}

static __device__ __forceinline__ float blockReduce(float v, bool isMax, float* red4, int lane, int wv){
  #pragma unroll
  for (int m=32;m>0;m>>=1){
    float o = __shfl_xor(v, m);
    v = isMax ? fmaxf(v,o) : v+o;
  }
  __syncthreads();
  if (lane==0) red4[wv] = v;
  __syncthreads();
  float r0=red4[0], r1=red4[1], r2=red4[2], r3=red4[3];
  return isMax ? fmaxf(fmaxf(r0,r1),fmaxf(r2,r3)) : (r0+r1)+(r2+r3);
}

// A-role: batch b = g*4+(s&3), M rows [chunk*64, +64) in LDS (chunk = s>>2).
// B-role: gate cols [s*64, s*64+64) for the group's 4 batches (16x16x32 MFMA,
// A-rows = 4 batches x4 dup, each wave owns 16 cols with full K).
__global__ __launch_bounds__(256,1) void scan_k(
    const int* __restrict__ src, const float* __restrict__ Wemb,
    const float* __restrict__ o_all, const unsigned short* __restrict__ Wcomb,
    const float* __restrict__ bcomb,
    float* __restrict__ dbuf, float* __restrict__ mglob,
    float* __restrict__ hbuf, float* __restrict__ out,
    int* __restrict__ cnts){
  __shared__ __align__(16) float Mrow[64*512];          // 128 KB
  __shared__ __align__(16) char ubuf[8256];             // mst f32[4][512] | xl bf16[4][1032]
  __shared__ __align__(16) float gates[4][68];
  __shared__ float z_lds[512];
  __shared__ float red4[4];
  __shared__ float zt_own[64], zp_own[64];

  const int tid = threadIdx.x, lane = tid & 63, wv = tid >> 6;
  const int bid = blockIdx.x;
  const int g = bid & 7, s = bid >> 3;
  const int b = g*4 + (s & 3), chunk = s >> 2;
  const int cbase = chunk*64;
  const int n0 = s*64;                       // B-role gate-col base
  int* bcnt = cnts + g*64;                   // per-group counter (256B stride)
  const int cA = lane*4, cB = 256 + lane*4;

  // ---------- init: zero m (both parities) + h_{-1}, M0 gather, d_0 ----------
  if (tid < 64){
    st_ag(&mglob[((size_t)0*B_SZ + b)*H_DIM + cbase + tid], 0.f);
    st_ag(&mglob[((size_t)1*B_SZ + b)*H_DIM + cbase + tid], 0.f);
    st_ag(&hbuf[((size_t)1*B_SZ + b)*H_DIM + cbase + tid], 0.f);   // h_{-1}=0
  }
  z_lds[tid] = 0.f; z_lds[tid+256] = 0.f;
  {
    const float* o0 = o_all + (size_t)b*H_DIM;
    f32x4 osA = *(const f32x4*)&o0[cA];
    f32x4 osB = *(const f32x4*)&o0[cB];
    for (int rr=0; rr<16; ++rr){
      int lr = wv*16 + rr;
      int sgl = cbase + lr;
      int idx = src[sgl*B_SZ + b];
      const float* wp = Wemb + (size_t)idx*H_DIM;
      f32x4 v0 = *(const f32x4*)&wp[cA];
      f32x4 v1 = *(const f32x4*)&wp[cB];
      *(f32x4*)&Mrow[lr*512 + cA] = v0;
      *(f32x4*)&Mrow[lr*512 + cB] = v1;
      float dd = v0[0]*osA[0]+v0[1]*osA[1]+v0[2]*osA[2]+v0[3]*osA[3]
               + v1[0]*osB[0]+v1[1]*osB[1]+v1[2]*osB[2]+v1[3]*osB[3];
      #pragma unroll
      for (int m=32;m>0;m>>=1) dd += __shfl_xor(dd, m);
      if (lane==0) st_ag(&dbuf[(size_t)b*S_LEN + sgl], dd);   // d_0, parity 0
    }
  }
  int tgt = 32;
  gbar(bcnt, tid, tgt); tgt += 32;           // group-local init barrier

  for (int t=0; t<S_LEN; ++t){
    const int pw = t & 1, po = pw ^ 1;
    const float* dR = dbuf + ((size_t)pw*B_SZ + b)*S_LEN;   // d_t
    float* dW = dbuf + ((size_t)po*B_SZ + b)*S_LEN;         // d_{t+1}
    const float* hR = hbuf + ((size_t)po*B_SZ + b)*H_DIM;   // h_{t-1}
    const float* ot = o_all + ((size_t)t*B_SZ + b)*H_DIM;

    // zero opposite-parity m slice for step t+1 (B(t-1) done reading it)
    if (tid < 64) st_ag(&mglob[((size_t)po*B_SZ + b)*H_DIM + cbase + tid], 0.f);

    // ---- cross-block loads (AGENT), issued together ----
    f32x2 d2  = ld2_ag(&dR[2*tid]);
    f32x2 hp2 = ld2_ag(&hR[2*tid]);
    f32x2 a0 = ld2_ag(&hR[cA]), a1 = ld2_ag(&hR[cA+2]);
    f32x2 b0 = ld2_ag(&hR[cB]), b1 = ld2_ag(&hR[cB+2]);
    f32x4 hA4 = (f32x4){a0[0],a0[1],a1[0],a1[1]};
    f32x4 hB4 = (f32x4){b0[0],b0[1],b1[0],b1[1]};

    // ---- hdot = h_{t-1}·o_t (block-local; t=0: zp=0 makes it moot) ----
    f32x2 ot2 = *(const f32x2*)&ot[2*tid];
    float hd = blockReduce(hp2[0]*ot2[0] + hp2[1]*ot2[1], false, red4, lane, wv);

    // ---- scores + softmax (z_{t-1} block-local) ----
    float zp0 = z_lds[2*tid], zp1 = z_lds[2*tid+1];
    float sc0 = (1.f - zp0)*d2[0] + zp0*hd;
    float sc1 = (1.f - zp1)*d2[1] + zp1*hd;
    float mx = blockReduce(fmaxf(sc0,sc1), true, red4, lane, wv);
    float ex0 = __expf(sc0 - mx), ex1 = __expf(sc1 - mx);
    float sm = blockReduce(ex0+ex1, false, red4, lane, wv);
    float inv = 1.f / sm;
    float zt0 = ex0*inv, zt1 = ex1*inv;
    z_lds[2*tid] = zt0; z_lds[2*tid+1] = zt1;
    {
      unsigned r = (unsigned)(2*tid) - (unsigned)cbase;
      if (r < 64u){ zt_own[r] = zt0; zp_own[r] = zp0; zt_own[r+1] = zt1; zp_own[r+1] = zp1; }
    }
    __syncthreads();

    // ---- single M sweep: pending update + m accum + next-d dot ----
    const bool hasNext = (t < S_LEN-1);
    const float* onx = o_all + ((size_t)(hasNext? t+1 : t)*B_SZ + b)*H_DIM;
    f32x4 osA = *(const f32x4*)&onx[cA];
    f32x4 osB = *(const f32x4*)&onx[cB];
    float m0=0,m1=0,m2=0,m3=0,m4=0,m5=0,m6=0,m7=0;
    for (int rr=0; rr<16; ++rr){
      int lr = wv*16 + rr;
      float zp = zp_own[lr], zt = zt_own[lr];
      float* mpA = &Mrow[lr*512 + cA];
      float* mpB = &Mrow[lr*512 + cB];
      f32x4 v0 = *(f32x4*)mpA;
      f32x4 v1 = *(f32x4*)mpB;
      v0[0] += zp*(hA4[0]-v0[0]); v0[1] += zp*(hA4[1]-v0[1]);
      v0[2] += zp*(hA4[2]-v0[2]); v0[3] += zp*(hA4[3]-v0[3]);
      v1[0] += zp*(hB4[0]-v1[0]); v1[1] += zp*(hB4[1]-v1[1]);
      v1[2] += zp*(hB4[2]-v1[2]); v1[3] += zp*(hB4[3]-v1[3]);
      *(f32x4*)mpA = v0; *(f32x4*)mpB = v1;
      m0 += zt*v0[0]; m1 += zt*v0[1]; m2 += zt*v0[2]; m3 += zt*v0[3];
      m4 += zt*v1[0]; m5 += zt*v1[1]; m6 += zt*v1[2]; m7 += zt*v1[3];
      float dd = v0[0]*osA[0]+v0[1]*osA[1]+v0[2]*osA[2]+v0[3]*osA[3]
               + v1[0]*osB[0]+v1[1]*osB[1]+v1[2]*osB[2]+v1[3]*osB[3];
      #pragma unroll
      for (int m=32;m>0;m>>=1) dd += __shfl_xor(dd, m);
      if (lane==0 && hasNext) st_ag(&dW[cbase + lr], dd);
    }
    __syncthreads();
    {
      float* mst = (float*)ubuf;
      *(f32x4*)&mst[wv*512 + cA] = (f32x4){m0,m1,m2,m3};
      *(f32x4*)&mst[wv*512 + cB] = (f32x4){m4,m5,m6,m7};
      __syncthreads();
      int i0 = tid*2;
      float s0v = mst[i0]   + mst[512+i0]   + mst[1024+i0]   + mst[1536+i0];
      float s1v = mst[i0+1] + mst[512+i0+1] + mst[1024+i0+1] + mst[1536+i0+1];
      float* mg = mglob + ((size_t)pw*B_SZ + b)*H_DIM;
      atomicAdd(&mg[i0],   s0v);     // device-scope fp32 atomic (MALL) — proven r2/r3
      atomicAdd(&mg[i0+1], s1v);
    }
    gbar(bcnt, tid, tgt); tgt += 32;

    // ---- phase B: gates[4 group-batches][cols n0..n0+64) = [o_t|m_t]·W_comb^T ----
    {
      unsigned short* xl = (unsigned short*)ubuf;   // [4][1032] bf16
      {
        const int q = wv, idx = lane*8;             // wave q stages batch q
        const int gb = g*4 + q;
        const float* oB = o_all + ((size_t)t*B_SZ + gb)*H_DIM;
        f32x4 o0 = *(const f32x4*)&oB[idx];
        f32x4 o1 = *(const f32x4*)&oB[idx+4];
        *(short8*)&xl[q*1032 + idx] = cvt8e(o0,o1);
        const float* mg = mglob + ((size_t)pw*B_SZ + gb)*H_DIM;
        f32x2 q0 = ld2_ag(mg+idx),   q1 = ld2_ag(mg+idx+2);
        f32x2 q2 = ld2_ag(mg+idx+4), q3 = ld2_ag(mg+idx+6);
        f32x4 f0 = (f32x4){q0[0],q0[1],q1[0],q1[1]};
        f32x4 f1 = (f32x4){q2[0],q2[1],q3[0],q3[1]};
        *(short8*)&xl[q*1032 + 512 + idx] = cvt8e(f0,f1);
      }
      __syncthreads();
      {
        const int r15 = lane & 15, q8 = (lane>>4)*8;
        const unsigned short* wp = Wcomb + (size_t)(n0 + wv*16 + r15)*KC;
        f32x4 acc = {0,0,0,0};
        #pragma unroll
        for (int kt=0; kt<32; ++kt){
          int k = kt*32 + q8;
          short8 af = *(const short8*)&xl[(r15&3)*1032 + k];
          short8 bf = *(const short8*)&wp[k];
          acc = __builtin_amdgcn_mfma_f32_16x16x32_bf16(af, bf, acc, 0,0,0);
        }
        if (lane < 16){
          #pragma unroll
          for (int r=0;r<4;++r) gates[r][wv*16 + r15] = acc[r];   // r = batch row
        }
      }
      __syncthreads();
      if (tid < 64){
        int q = tid >> 4, p = tid & 15;     // batch q, h-idx p within block's 16
        int gb = g*4 + q;
        int hq = s*16 + p;                  // global h' index
        float g4[4];
        #pragma unroll
        for (int gg2=0; gg2<4; ++gg2)
          g4[gg2] = gates[q][p*4+gg2] + bcomb[n0 + p*4+gg2];
        float ccv = sigf(g4[0])*tanh_(g4[2]);
        float hh  = sigf(g4[3])*tanh_(ccv);
        st_ag(&hbuf[((size_t)pw*B_SZ + gb)*H_DIM + hq], hh);
        out[((size_t)t*B_SZ + gb)*H_DIM + hq] = hh;
        if (t == S_LEN-1){
          out[(size_t)S_LEN*B_SZ*H_DIM + (size_t)gb*H_DIM + hq] = hh;
          out[(size_t)S_LEN*B_SZ*H_DIM + (size_t)B_SZ*H_DIM + (size_t)gb*H_DIM + hq] = ccv;
        }
      }
    }
    gbar(bcnt, tid, tgt); tgt += 32;
  }
}

// ------------------- host launch -------------------
extern "C" void kernel_launch(void* const* d_in, const int* in_sizes, int n_in,
                              void* d_out, int out_size, void* d_ws, size_t ws_size,
                              hipStream_t stream){
  const int*   src   = (const int*)  d_in[0];
  const float* Wemb  = (const float*)d_in[1];
  const float* Wihr  = (const float*)d_in[2];
  const float* bihr  = (const float*)d_in[3];
  const float* bhhr  = (const float*)d_in[4];
  const float* Wc    = (const float*)d_in[5];
  const float* bc    = (const float*)d_in[6];
  const float* Wihw  = (const float*)d_in[7];
  const float* bihw  = (const float*)d_in[8];
  const float* bhhw  = (const float*)d_in[9];
  float* out = (float*)d_out;

  char* ws = (char*)d_ws;
  size_t off = 0;
  auto alloc = [&](size_t bytes)->char*{
    char* p = ws + off; off += (bytes + 255) & ~(size_t)255; return p;
  };
  unsigned short* embB  = (unsigned short*)alloc((size_t)16384*512*2);
  float*          o_all = (float*)         alloc((size_t)16384*512*4);
  unsigned short* WrP   = (unsigned short*)alloc((size_t)2048*512*2);
  unsigned short* WiwP  = (unsigned short*)alloc((size_t)2048*1024*2);
  unsigned short* WcT   = (unsigned short*)alloc((size_t)1024*1024*2);
  unsigned short* Wcomb = (unsigned short*)alloc((size_t)2048*1024*2);
  float*          bperm = (float*)alloc(2048*4);
  float*          bcomb = (float*)alloc(2048*4);
  float*          dbuf  = (float*)alloc((size_t)2*32*512*4);
  float*          mglob = (float*)alloc((size_t)2*32*512*4);
  float*          hbuf  = (float*)alloc((size_t)2*32*512*4);
  int*            cnts  = (int*)  alloc(4096);

  hipMemsetAsync(cnts, 0, 4096, stream);
  k_gather_emb<<<4096,256,0,stream>>>(src, Wemb, embB);
  k_perm_wr  <<<512, 256,0,stream>>>(Wihr, WrP);
  k_perm_wihw<<<1024,256,0,stream>>>(Wihw, WiwP);
  k_wcT      <<<256, 256,0,stream>>>(Wc, WcT);
  k_bias_r   <<<8,   256,0,stream>>>(bihr, bhhr, bperm);
  k_bcomb    <<<8,   256,0,stream>>>(Wihw, bc, bihw, bhhw, bcomb);
  gemm_k<0><<<2048,256,0,stream>>>(embB, WrP, 512, 16, bperm, o_all, nullptr, 0);
  gemm_k<1><<<128,256,0,stream>>>(WiwP, WcT, 1024, 8, nullptr, nullptr, Wcomb, 1024);
  scan_k<<<256,256,0,stream>>>(src, Wemb, o_all, Wcomb, bcomb,
                               dbuf, mglob, hbuf, out, cnts);
}